// Round 17
// baseline (401.907 us; speedup 1.0000x reference)
//
#include <hip/hip_runtime.h>

typedef __bf16 bf16_t;
typedef __bf16 bf16x8 __attribute__((ext_vector_type(8)));
typedef float  f32x4  __attribute__((ext_vector_type(4)));

#define NB    64
#define EB    4032            // NB*(NB-1)
#define BATCH 32
#define H     256
#define M_EDGE (BATCH*EB)     // 129024
#define M_NODE (BATCH*NB)     // 2048
#define T2    4               // m2: M-tiles per block

__device__ __forceinline__ void load_lds16(const void* g, void* l) {
    __builtin_amdgcn_global_load_lds(
        (const __attribute__((address_space(1))) unsigned int*)g,
        (__attribute__((address_space(3))) unsigned int*)l, 16, 0, 0);
}
// fast ELU: v_exp_f32 (+mul) instead of ~35-inst expm1f; bf16-rounding dwarfs the error
__device__ __forceinline__ float elu(float v) { return v > 0.f ? v : __expf(v) - 1.f; }

// ---------------------------------------------------------------------------
// Fused 2-layer node MLP: out = ELU(ELU(A@W1+b1)@W2+b2), 64 rows/block, K1=256.
// ---------------------------------------------------------------------------
template<bool AF32>
__global__ __launch_bounds__(256)
void fused_mlp(const void* __restrict__ A0v,
               const bf16_t* __restrict__ W1t, const float* __restrict__ b1,
               const bf16_t* __restrict__ W2t, const float* __restrict__ b2,
               bf16_t* __restrict__ out, float* __restrict__ stats)
{
    const int m0 = blockIdx.x * 64;
    const int tid = threadIdx.x, wave = tid >> 6, lane = tid & 63;
    const int l15 = lane & 15, quad = lane >> 4;
    const int row = tid >> 2;
    const int cx8 = (((tid & 3) ^ ((tid >> 3) & 3))) * 8;
    const int sl8 = (tid & 3) * 8;
    const int xq8 = (quad ^ ((l15 >> 1) & 3)) * 8;

    __shared__ bf16_t h1s[64 * 264];
    __shared__ bf16_t Bs[256 * 32];
    __shared__ float  sred[512];

    const bf16_t* A0 = (const bf16_t*)A0v;

    f32x4 acc1[4][4];
#pragma unroll
    for (int t = 0; t < 4; ++t)
#pragma unroll
        for (int u = 0; u < 4; ++u) acc1[t][u] = (f32x4){0.f, 0.f, 0.f, 0.f};

    for (int k0 = 0; k0 < 256; k0 += 32) {
        bf16_t* ldsA = h1s + wave * 512;
        if (AF32) {
            const float* af = (const float*)A0v + (size_t)(m0 + row) * 256 + k0 + cx8;
            float4 lo = *(const float4*)af;
            float4 hi = *(const float4*)(af + 4);
            bf16x8 v;
            v[0]=(bf16_t)lo.x; v[1]=(bf16_t)lo.y; v[2]=(bf16_t)lo.z; v[3]=(bf16_t)lo.w;
            v[4]=(bf16_t)hi.x; v[5]=(bf16_t)hi.y; v[6]=(bf16_t)hi.z; v[7]=(bf16_t)hi.w;
            *(bf16x8*)&h1s[row * 32 + sl8] = v;
        } else {
            load_lds16(A0 + (size_t)(m0 + row) * 256 + k0 + cx8, ldsA);
        }
#pragma unroll
        for (int p = 0; p < 4; ++p)
            load_lds16(W1t + (size_t)(p * 64 + row) * 256 + k0 + cx8,
                       Bs + (p * 256 + wave * 64) * 8);
        __syncthreads();
        bf16x8 afr[4], bfr[4];
#pragma unroll
        for (int t = 0; t < 4; ++t)
            afr[t] = *(const bf16x8*)&h1s[(t * 16 + l15) * 32 + xq8];
#pragma unroll
        for (int u = 0; u < 4; ++u)
            bfr[u] = *(const bf16x8*)&Bs[(wave * 64 + u * 16 + l15) * 32 + xq8];
#pragma unroll
        for (int t = 0; t < 4; ++t)
#pragma unroll
            for (int u = 0; u < 4; ++u)
                acc1[t][u] = __builtin_amdgcn_mfma_f32_16x16x32_bf16(afr[t], bfr[u], acc1[t][u], 0, 0, 0);
        __syncthreads();
    }

#pragma unroll
    for (int u = 0; u < 4; ++u) {
        int   col = wave * 64 + u * 16 + l15;
        float bv  = b1[col];
#pragma unroll
        for (int t = 0; t < 4; ++t)
#pragma unroll
            for (int r = 0; r < 4; ++r)
                h1s[(t * 16 + quad * 4 + r) * 264 + col] = (bf16_t)elu(acc1[t][u][r] + bv);
    }
    sred[tid] = 0.f; sred[256 + tid] = 0.f;
    __syncthreads();

    f32x4 acc2[4][4];
#pragma unroll
    for (int t = 0; t < 4; ++t)
#pragma unroll
        for (int u = 0; u < 4; ++u) acc2[t][u] = (f32x4){0.f, 0.f, 0.f, 0.f};

    for (int k0 = 0; k0 < 256; k0 += 32) {
#pragma unroll
        for (int p = 0; p < 4; ++p)
            load_lds16(W2t + (size_t)(p * 64 + row) * 256 + k0 + cx8,
                       Bs + (p * 256 + wave * 64) * 8);
        __syncthreads();
        bf16x8 afr[4], bfr[4];
#pragma unroll
        for (int t = 0; t < 4; ++t)
            afr[t] = *(const bf16x8*)&h1s[(t * 16 + l15) * 264 + k0 + quad * 8];
#pragma unroll
        for (int u = 0; u < 4; ++u)
            bfr[u] = *(const bf16x8*)&Bs[(wave * 64 + u * 16 + l15) * 32 + xq8];
#pragma unroll
        for (int t = 0; t < 4; ++t)
#pragma unroll
            for (int u = 0; u < 4; ++u)
                acc2[t][u] = __builtin_amdgcn_mfma_f32_16x16x32_bf16(afr[t], bfr[u], acc2[t][u], 0, 0, 0);
        __syncthreads();
    }

#pragma unroll
    for (int u = 0; u < 4; ++u) {
        int   col = wave * 64 + u * 16 + l15;
        float bv  = b2[col];
        float s = 0.f, q = 0.f;
#pragma unroll
        for (int t = 0; t < 4; ++t)
#pragma unroll
            for (int r = 0; r < 4; ++r) {
                float v = elu(acc2[t][u][r] + bv);
                h1s[(t * 16 + quad * 4 + r) * 264 + col] = (bf16_t)v;
                s += v; q += v * v;
            }
        s += __shfl_xor(s, 16); s += __shfl_xor(s, 32);
        q += __shfl_xor(q, 16); q += __shfl_xor(q, 32);
        if (quad == 0) { atomicAdd(&sred[col], s); atomicAdd(&sred[256 + col], q); }
    }
    __syncthreads();
#pragma unroll
    for (int p = 0; p < 8; ++p) {
        int idx = p * 256 + tid;
        int r = idx >> 5, ch = idx & 31;
        *(uint4*)&out[(size_t)(m0 + r) * H + ch * 8] = *(const uint4*)&h1s[r * 264 + ch * 8];
    }
    atomicAdd(&stats[tid],     sred[tid]);
    atomicAdd(&stats[H + tid], sred[256 + tid]);
}

// ---------------------------------------------------------------------------
// Node GEMM w/ BN fold on A: out[M,512] = (A*scale+shift)[M,256] @ Wt^T + bias.
// ---------------------------------------------------------------------------
__global__ __launch_bounds__(256)
void node_gemm(const bf16_t* __restrict__ A, const float* __restrict__ scA,
               const bf16_t* __restrict__ Wt, const float* __restrict__ bias,
               float* __restrict__ out)
{
    const int m0 = blockIdx.x * 64;
    const int nb = blockIdx.y * 256;
    const int tid = threadIdx.x, wave = tid >> 6, lane = tid & 63;
    const int l15 = lane & 15, quad = lane >> 4;
    const int row = tid >> 2;
    const int cx8 = (((tid & 3) ^ ((tid >> 3) & 3))) * 8;
    const int sl8 = (tid & 3) * 8;
    const int xq8 = (quad ^ ((l15 >> 1) & 3)) * 8;
    __shared__ bf16_t As[64 * 32];
    __shared__ bf16_t Bs[256 * 32];

    f32x4 acc[4][4];
#pragma unroll
    for (int t = 0; t < 4; ++t)
#pragma unroll
        for (int u = 0; u < 4; ++u) acc[t][u] = (f32x4){0.f, 0.f, 0.f, 0.f};

    for (int k0 = 0; k0 < 256; k0 += 32) {
        {   // BN-folded A staging (VGPR path)
            int kc = k0 + cx8;
            bf16x8 v = *(const bf16x8*)(A + (size_t)(m0 + row) * 256 + kc);
            bf16x8 w;
#pragma unroll
            for (int j = 0; j < 8; ++j)
                w[j] = (bf16_t)((float)v[j] * scA[kc + j] + scA[H + kc + j]);
            *(bf16x8*)&As[row * 32 + sl8] = w;
        }
#pragma unroll
        for (int p = 0; p < 4; ++p)
            load_lds16(Wt + (size_t)(nb + p * 64 + row) * 256 + k0 + cx8,
                       Bs + (p * 256 + wave * 64) * 8);
        __syncthreads();
        bf16x8 afr[4], bfr[4];
#pragma unroll
        for (int t = 0; t < 4; ++t)
            afr[t] = *(const bf16x8*)&As[(t * 16 + l15) * 32 + xq8];
#pragma unroll
        for (int u = 0; u < 4; ++u)
            bfr[u] = *(const bf16x8*)&Bs[(wave * 64 + u * 16 + l15) * 32 + xq8];
#pragma unroll
        for (int t = 0; t < 4; ++t)
#pragma unroll
            for (int u = 0; u < 4; ++u)
                acc[t][u] = __builtin_amdgcn_mfma_f32_16x16x32_bf16(afr[t], bfr[u], acc[t][u], 0, 0, 0);
        __syncthreads();
    }
#pragma unroll
    for (int u = 0; u < 4; ++u) {
        int col = nb + wave * 64 + u * 16 + l15;
        float bv = bias[col];
#pragma unroll
        for (int t = 0; t < 4; ++t)
#pragma unroll
            for (int r = 0; r < 4; ++r)
                out[(size_t)(m0 + t * 16 + quad * 4 + r) * 512 + col] = acc[t][u][r] + bv;
    }
}

// ---------------------------------------------------------------------------
// MLP2, PIPELINED B-STATIONARY (R13 winner): W2b frags in regs; T2 M-tiles
// per block; A tile t+1 computed into alt LDS buffer while MFMA consumes t.
// ---------------------------------------------------------------------------
__global__ __launch_bounds__(256, 2)
void m2_kernel(const float* __restrict__ PQ, const bf16_t* __restrict__ W2t,
               const float* __restrict__ b2, bf16_t* __restrict__ out,
               float* __restrict__ stats)
{
    const int tile0 = blockIdx.x * T2;   // 64-row tiles
    const int tid = threadIdx.x, wave = tid >> 6, lane = tid & 63;
    const int l15 = lane & 15, quad = lane >> 4;

    __shared__ bf16_t Abuf[2][64 * 264];
    __shared__ float  sred[512];

    bf16x8 Breg[32];
#pragma unroll
    for (int ks = 0; ks < 8; ++ks)
#pragma unroll
        for (int u = 0; u < 4; ++u) {
            int col = wave * 64 + u * 16 + l15;
            Breg[ks * 4 + u] = *(const bf16x8*)(W2t + (size_t)col * 256 + ks * 32 + quad * 8);
        }
    sred[tid] = 0.f; sred[256 + tid] = 0.f;

    auto computeA = [&](int t, int b) {
        int row = tid >> 2;
        int m = (tile0 + t) * 64 + row;
        int bb = m / EB, e = m - bb * EB;
        int sn = e / (NB - 1), rr = e - sn * (NB - 1);
        int rc = rr + (rr >= sn ? 1 : 0);
        const float* Prow = PQ + (size_t)(bb * NB + sn) * 512;
        const float* Qrow = PQ + (size_t)(bb * NB + rc) * 512 + 256;
        int c0 = (tid & 3) * 64;
#pragma unroll
        for (int j = 0; j < 8; ++j) {
            int c = c0 + j * 8;
            float4 p0 = *(const float4*)(Prow + c);
            float4 p1 = *(const float4*)(Prow + c + 4);
            float4 q0 = *(const float4*)(Qrow + c);
            float4 q1 = *(const float4*)(Qrow + c + 4);
            bf16x8 v;
            v[0]=(bf16_t)elu(p0.x+q0.x); v[1]=(bf16_t)elu(p0.y+q0.y);
            v[2]=(bf16_t)elu(p0.z+q0.z); v[3]=(bf16_t)elu(p0.w+q0.w);
            v[4]=(bf16_t)elu(p1.x+q1.x); v[5]=(bf16_t)elu(p1.y+q1.y);
            v[6]=(bf16_t)elu(p1.z+q1.z); v[7]=(bf16_t)elu(p1.w+q1.w);
            *(bf16x8*)&Abuf[b][row * 264 + c] = v;
        }
    };

    computeA(0, 0);
    __syncthreads();

    for (int t = 0; t < T2; ++t) {
        const int cur = t & 1, nxt = cur ^ 1;
        if (t + 1 < T2) computeA(t + 1, nxt);

        f32x4 acc[4][4];
#pragma unroll
        for (int a = 0; a < 4; ++a)
#pragma unroll
            for (int u = 0; u < 4; ++u) acc[a][u] = (f32x4){0.f, 0.f, 0.f, 0.f};
#pragma unroll
        for (int ks = 0; ks < 8; ++ks) {
            bf16x8 afr[4];
#pragma unroll
            for (int a = 0; a < 4; ++a)
                afr[a] = *(const bf16x8*)&Abuf[cur][(a * 16 + l15) * 264 + ks * 32 + quad * 8];
#pragma unroll
            for (int a = 0; a < 4; ++a)
#pragma unroll
                for (int u = 0; u < 4; ++u)
                    acc[a][u] = __builtin_amdgcn_mfma_f32_16x16x32_bf16(afr[a], Breg[ks * 4 + u], acc[a][u], 0, 0, 0);
        }
        __syncthreads();

#pragma unroll
        for (int u = 0; u < 4; ++u) {
            int   col = wave * 64 + u * 16 + l15;
            float bv  = b2[col];
            float s = 0.f, q = 0.f;
#pragma unroll
            for (int a = 0; a < 4; ++a)
#pragma unroll
                for (int r = 0; r < 4; ++r) {
                    float v = elu(acc[a][u][r] + bv);
                    Abuf[cur][(a * 16 + quad * 4 + r) * 264 + col] = (bf16_t)v;
                    s += v; q += v * v;
                }
            s += __shfl_xor(s, 16); s += __shfl_xor(s, 32);
            q += __shfl_xor(q, 16); q += __shfl_xor(q, 32);
            if (quad == 0) { atomicAdd(&sred[col], s); atomicAdd(&sred[256 + col], q); }
        }
        __syncthreads();

        size_t m0 = (size_t)(tile0 + t) * 64;
#pragma unroll
        for (int p = 0; p < 8; ++p) {
            int idx = p * 256 + tid;
            int r = idx >> 5, ch = idx & 31;
            *(uint4*)&out[(m0 + r) * H + ch * 8] = *(const uint4*)&Abuf[cur][r * 264 + ch * 8];
        }
        __syncthreads();
    }
    atomicAdd(&stats[tid],     sred[tid]);
    atomicAdd(&stats[H + tid], sred[256 + tid]);
}

// ---------------------------------------------------------------------------
// MLP4 fused: W4b persistent in 128 VGPRs (loaded ONCE at kernel start, the
// m2-proven pattern); L1 keeps R10 staged form (Wsk via LDS); L2 is
// barrier-free ds_read+MFMA with Breg. RS add + stats unchanged.
// ---------------------------------------------------------------------------
__global__ __launch_bounds__(256, 2)
void m4_kernel(const bf16_t* __restrict__ h2, const bf16_t* __restrict__ Wskt,
               const float* __restrict__ RS, const bf16_t* __restrict__ W2t,
               const float* __restrict__ b2, bf16_t* __restrict__ out,
               float* __restrict__ stats)
{
    const int m0 = blockIdx.x * 64;
    const int tid = threadIdx.x, wave = tid >> 6, lane = tid & 63;
    const int l15 = lane & 15, quad = lane >> 4;
    const int row = tid >> 2;
    const int cx8 = (((tid & 3) ^ ((tid >> 3) & 3))) * 8;
    const int xq8 = (quad ^ ((l15 >> 1) & 3)) * 8;

    __shared__ bf16_t h1s[64 * 264];
    __shared__ bf16_t Bs[256 * 32];
    __shared__ float  sred[512];
    __shared__ int    sndN[64], rcvN[64];

    // W4b fragments -> 128 VGPRs, ONCE, before all loops (m2-proven pattern)
    bf16x8 Breg[32];
#pragma unroll
    for (int ks = 0; ks < 8; ++ks)
#pragma unroll
        for (int u = 0; u < 4; ++u) {
            int col = wave * 64 + u * 16 + l15;
            Breg[ks * 4 + u] = *(const bf16x8*)(W2t + (size_t)col * 256 + ks * 32 + quad * 8);
        }

    if (tid < 64) {
        int m = m0 + tid, bb = m / EB, e = m - bb * EB;
        int sn = e / (NB - 1), rr = e - sn * (NB - 1);
        int rc = rr + (rr >= sn ? 1 : 0);
        sndN[tid] = bb * NB + sn;
        rcvN[tid] = bb * NB + rc;
    }

    f32x4 acc1[4][4];
#pragma unroll
    for (int t = 0; t < 4; ++t)
#pragma unroll
        for (int u = 0; u < 4; ++u) acc1[t][u] = (f32x4){0.f, 0.f, 0.f, 0.f};

    for (int k0 = 0; k0 < 256; k0 += 32) {
        load_lds16(h2 + (size_t)(m0 + row) * 256 + k0 + cx8, h1s + wave * 512);
#pragma unroll
        for (int p = 0; p < 4; ++p)
            load_lds16(Wskt + (size_t)(p * 64 + row) * 256 + k0 + cx8,
                       Bs + (p * 256 + wave * 64) * 8);
        __syncthreads();
        bf16x8 afr[4], bfr[4];
#pragma unroll
        for (int t = 0; t < 4; ++t)
            afr[t] = *(const bf16x8*)&h1s[(t * 16 + l15) * 32 + xq8];
#pragma unroll
        for (int u = 0; u < 4; ++u)
            bfr[u] = *(const bf16x8*)&Bs[(wave * 64 + u * 16 + l15) * 32 + xq8];
#pragma unroll
        for (int t = 0; t < 4; ++t)
#pragma unroll
            for (int u = 0; u < 4; ++u)
                acc1[t][u] = __builtin_amdgcn_mfma_f32_16x16x32_bf16(afr[t], bfr[u], acc1[t][u], 0, 0, 0);
        __syncthreads();
    }

    // spill acc1 (pre-activation) to LDS in row-major layout
#pragma unroll
    for (int u = 0; u < 4; ++u) {
        int col = wave * 64 + u * 16 + l15;
#pragma unroll
        for (int t = 0; t < 4; ++t)
#pragma unroll
            for (int r = 0; r < 4; ++r)
                h1s[(t * 16 + quad * 4 + r) * 264 + col] = (bf16_t)acc1[t][u][r];
    }
    sred[tid] = 0.f; sred[256 + tid] = 0.f;
    __syncthreads();

    // row-wise coalesced RS add + ELU (send row L1-cached: <=2 senders/block)
    {
        const float* Srow = RS + (size_t)sndN[row] * 512;
        const float* Rrow = RS + (size_t)rcvN[row] * 512 + 256;
        int c0 = (tid & 3) * 64;
#pragma unroll
        for (int j = 0; j < 8; ++j) {
            int c = c0 + j * 8;
            bf16x8 h = *(const bf16x8*)&h1s[row * 264 + c];
            float4 s0 = *(const float4*)(Srow + c);
            float4 s1 = *(const float4*)(Srow + c + 4);
            float4 r0 = *(const float4*)(Rrow + c);
            float4 r1 = *(const float4*)(Rrow + c + 4);
            bf16x8 v;
            v[0]=(bf16_t)elu((float)h[0]+s0.x+r0.x); v[1]=(bf16_t)elu((float)h[1]+s0.y+r0.y);
            v[2]=(bf16_t)elu((float)h[2]+s0.z+r0.z); v[3]=(bf16_t)elu((float)h[3]+s0.w+r0.w);
            v[4]=(bf16_t)elu((float)h[4]+s1.x+r1.x); v[5]=(bf16_t)elu((float)h[5]+s1.y+r1.y);
            v[6]=(bf16_t)elu((float)h[6]+s1.z+r1.z); v[7]=(bf16_t)elu((float)h[7]+s1.w+r1.w);
            *(bf16x8*)&h1s[row * 264 + c] = v;
        }
    }
    __syncthreads();

    // L2: barrier-free ds_read+MFMA with persistent W4b fragments
    f32x4 acc2[4][4];
#pragma unroll
    for (int t = 0; t < 4; ++t)
#pragma unroll
        for (int u = 0; u < 4; ++u) acc2[t][u] = (f32x4){0.f, 0.f, 0.f, 0.f};
#pragma unroll
    for (int ks = 0; ks < 8; ++ks) {
        bf16x8 afr[4];
#pragma unroll
        for (int t = 0; t < 4; ++t)
            afr[t] = *(const bf16x8*)&h1s[(t * 16 + l15) * 264 + ks * 32 + quad * 8];
#pragma unroll
        for (int t = 0; t < 4; ++t)
#pragma unroll
            for (int u = 0; u < 4; ++u)
                acc2[t][u] = __builtin_amdgcn_mfma_f32_16x16x32_bf16(afr[t], Breg[ks * 4 + u], acc2[t][u], 0, 0, 0);
    }
    __syncthreads();   // all waves done reading h1s before epilogue overwrite

#pragma unroll
    for (int u = 0; u < 4; ++u) {
        int   col = wave * 64 + u * 16 + l15;
        float bv  = b2[col];
        float s = 0.f, q = 0.f;
#pragma unroll
        for (int t = 0; t < 4; ++t)
#pragma unroll
            for (int r = 0; r < 4; ++r) {
                float v = elu(acc2[t][u][r] + bv);
                h1s[(t * 16 + quad * 4 + r) * 264 + col] = (bf16_t)v;
                s += v; q += v * v;
            }
        s += __shfl_xor(s, 16); s += __shfl_xor(s, 32);
        q += __shfl_xor(q, 16); q += __shfl_xor(q, 32);
        if (quad == 0) { atomicAdd(&sred[col], s); atomicAdd(&sred[256 + col], q); }
    }
    __syncthreads();
#pragma unroll
    for (int p = 0; p < 8; ++p) {
        int idx = p * 256 + tid;
        int r = idx >> 5, ch = idx & 31;
        *(uint4*)&out[(size_t)(m0 + r) * H + ch * 8] = *(const uint4*)&h1s[r * 264 + ch * 8];
    }
    atomicAdd(&stats[tid],     sred[tid]);
    atomicAdd(&stats[H + tid], sred[256 + tid]);
}

// ---------------------------------------------------------------------------
// prep: all static weight prep in ONE kernel (block-index dispatch).
// ---------------------------------------------------------------------------
__global__ void prep(const float* __restrict__ w1a, bf16_t* __restrict__ wt1a,
                     const float* __restrict__ w1b, bf16_t* __restrict__ wt1b,
                     const float* __restrict__ w2b, bf16_t* __restrict__ wt2b,
                     const float* __restrict__ w3a, bf16_t* __restrict__ wt3a,
                     const float* __restrict__ w3b, bf16_t* __restrict__ wt3b,
                     const float* __restrict__ w4b, bf16_t* __restrict__ wt4b,
                     const float* __restrict__ w2a, bf16_t* __restrict__ wtpq,
                     const float* __restrict__ w4a, bf16_t* __restrict__ wtrs,
                     const float* __restrict__ b2a, float* __restrict__ biasPQ,
                     float* __restrict__ stats)
{
    int blk = blockIdx.x, tid = threadIdx.x;
    if (blk < 1536) {
        int grp = blk >> 8, lb = blk & 255;
        const float* w; bf16_t* wt;
        switch (grp) {
            case 0: w = w1a; wt = wt1a; break;
            case 1: w = w1b; wt = wt1b; break;
            case 2: w = w2b; wt = wt2b; break;
            case 3: w = w3a; wt = wt3a; break;
            case 4: w = w3b; wt = wt3b; break;
            default: w = w4b; wt = wt4b; break;
        }
        int idx = lb * 256 + tid;
        int k = idx >> 8, n = idx & 255;
        wt[n * 256 + k] = (bf16_t)w[idx];
    } else if (blk < 2560) {
        int lb = blk - 1536;
        const float* w = (lb < 512) ? w2a : w4a;
        bf16_t* wt = (lb < 512) ? wtpq : wtrs;
        int c = lb & 511, k = tid;
        float v = (c < 256) ? w[k * 256 + c] : w[(256 + k) * 256 + (c - 256)];
        wt[c * 256 + k] = (bf16_t)v;
    } else if (blk == 2560) {
        biasPQ[tid] = b2a[tid];
        biasPQ[256 + tid] = 0.f;
    } else {
        for (int j = 0; j < 8; ++j) stats[j * 256 + tid] = 0.f;
    }
}

// prep2: blocks 0-255 build wsk; block 256 builds bias_rs (needs sc2)
__global__ void prep2(const float* __restrict__ w4a, const float* __restrict__ sc2,
                      const float* __restrict__ b4a, bf16_t* __restrict__ wt,
                      float* __restrict__ bias)
{
    int blk = blockIdx.x, tid = threadIdx.x;
    if (blk < 256) {
        wt[blk * 256 + tid] = (bf16_t)(w4a[(512 + tid) * 256 + blk] * sc2[tid]);
    } else {
        float acc = 0.f;
        for (int k = 0; k < 256; ++k)
            acc += sc2[256 + k] * w4a[(512 + k) * 256 + tid];
        bias[tid] = b4a[tid] + acc;
        bias[256 + tid] = 0.f;
    }
}

__global__ void bn_finalize(const float* __restrict__ stats,
                            const float* __restrict__ g, const float* __restrict__ beta,
                            float M, float* __restrict__ sc)
{
    int c = threadIdx.x;
    float mean = stats[c] / M;
    float var  = stats[H + c] / M - mean * mean;
    float scale = g[c] * rsqrtf(var + 1e-5f);
    sc[c]     = scale;
    sc[H + c] = beta[c] - mean * scale;
}

__global__ void edge2node(const bf16_t* __restrict__ x2, const float* __restrict__ sc,
                          bf16_t* __restrict__ inc)
{
    int bn = blockIdx.x, bb = bn >> 6, n = bn & 63;
    int g = threadIdx.x >> 5, t = threadIdx.x & 31;
    __shared__ float part[8][256];
    const bf16_t* base = x2 + (size_t)bb * EB * H;
    float a[8] = {0.f,0.f,0.f,0.f,0.f,0.f,0.f,0.f};
    for (int i = g; i < NB; i += 8) {
        if (i == n) continue;
        int e = i * (NB - 1) + n - (n > i ? 1 : 0);
        bf16x8 v = *(const bf16x8*)&base[(size_t)e * H + t * 8];
#pragma unroll
        for (int j = 0; j < 8; ++j) a[j] += (float)v[j];
    }
#pragma unroll
    for (int j = 0; j < 8; ++j) part[g][t * 8 + j] = a[j];
    __syncthreads();
    int c = threadIdx.x;
    float s = 0.f;
#pragma unroll
    for (int g2 = 0; g2 < 8; ++g2) s += part[g2][c];
    inc[(size_t)bn * H + c] = (bf16_t)(s * (1.f / 64.f) * sc[c] + sc[H + c] * (63.f / 64.f));
}

__global__ void fc_kernel(const bf16_t* __restrict__ x4, const float* __restrict__ sc,
                          const float* __restrict__ fcw, const float* __restrict__ fcb,
                          float* __restrict__ out)
{
    int row  = blockIdx.x * 8 + (threadIdx.x >> 5);
    int t    = threadIdx.x & 31;
    bf16x8 v8 = *(const bf16x8*)(x4 + (size_t)row * H + t * 8);
    float s0 = 0.f, s1 = 0.f;
#pragma unroll
    for (int j = 0; j < 8; ++j) {
        int c = t * 8 + j;
        float v = (float)v8[j] * sc[c] + sc[H + c];
        s0 += v * fcw[c * 2];
        s1 += v * fcw[c * 2 + 1];
    }
#pragma unroll
    for (int off = 16; off; off >>= 1) {
        s0 += __shfl_down(s0, off, 32);
        s1 += __shfl_down(s1, off, 32);
    }
    if (t == 0) {
        out[(size_t)row * 2]     = s0 + fcb[0];
        out[(size_t)row * 2 + 1] = s1 + fcb[1];
    }
}

// ---------------------------------------------------------------------------
extern "C" void kernel_launch(void* const* d_in, const int* in_sizes, int n_in,
                              void* d_out, int out_size, void* d_ws, size_t ws_size,
                              hipStream_t stream)
{
    (void)in_sizes; (void)n_in; (void)out_size; (void)ws_size;
    const float* inp = (const float*)d_in[0];
    const float* w1a = (const float*)d_in[3];  const float* b1a = (const float*)d_in[4];
    const float* w1b = (const float*)d_in[5];  const float* b1b = (const float*)d_in[6];
    const float* g1  = (const float*)d_in[7];  const float* be1 = (const float*)d_in[8];
    const float* w2a = (const float*)d_in[9];  const float* b2a = (const float*)d_in[10];
    const float* w2b = (const float*)d_in[11]; const float* b2b = (const float*)d_in[12];
    const float* g2  = (const float*)d_in[13]; const float* be2 = (const float*)d_in[14];
    const float* w3a = (const float*)d_in[15]; const float* b3a = (const float*)d_in[16];
    const float* w3b = (const float*)d_in[17]; const float* b3b = (const float*)d_in[18];
    const float* g3  = (const float*)d_in[19]; const float* be3 = (const float*)d_in[20];
    const float* w4a = (const float*)d_in[21]; const float* b4a = (const float*)d_in[22];
    const float* w4b = (const float*)d_in[23]; const float* b4b = (const float*)d_in[24];
    const float* g4  = (const float*)d_in[25]; const float* be4 = (const float*)d_in[26];
    const float* fcw = (const float*)d_in[27]; const float* fcb = (const float*)d_in[28];

    char* p = (char*)d_ws;
    auto alloc = [&](size_t nbytes) { char* r = p; p += (nbytes + 255) & ~(size_t)255; return r; };

    bf16_t* wt1a = (bf16_t*)alloc(256 * 256 * 2);
    bf16_t* wt1b = (bf16_t*)alloc(256 * 256 * 2);
    bf16_t* wt2b = (bf16_t*)alloc(256 * 256 * 2);
    bf16_t* wt3a = (bf16_t*)alloc(256 * 256 * 2);
    bf16_t* wt3b = (bf16_t*)alloc(256 * 256 * 2);
    bf16_t* wt4b = (bf16_t*)alloc(256 * 256 * 2);
    bf16_t* wtpq = (bf16_t*)alloc(512 * 256 * 2);
    bf16_t* wtrs = (bf16_t*)alloc(512 * 256 * 2);
    bf16_t* wtsk = (bf16_t*)alloc(256 * 256 * 2);
    float*  biasPQ = (float*)alloc(512 * sizeof(float));
    float*  biasRS = (float*)alloc(512 * sizeof(float));
    float*  stats  = (float*)alloc(4 * 512 * sizeof(float));
    float*  sc     = (float*)alloc(4 * 512 * sizeof(float));
    bf16_t* x1   = (bf16_t*)alloc((size_t)M_NODE * H * 2);
    bf16_t* incb = (bf16_t*)alloc((size_t)M_NODE * H * 2);
    bf16_t* x3   = (bf16_t*)alloc((size_t)M_NODE * H * 2);
    float*  PQ   = (float*)alloc((size_t)M_NODE * 512 * sizeof(float));
    float*  RS   = (float*)alloc((size_t)M_NODE * 512 * sizeof(float));
    bf16_t* h2   = (bf16_t*)alloc((size_t)M_EDGE * H * 2);
    bf16_t* h4   = (bf16_t*)alloc((size_t)M_EDGE * H * 2);

    // all static prep in one launch
    prep<<<2562, 256, 0, stream>>>(w1a, wt1a, w1b, wt1b, w2b, wt2b, w3a, wt3a,
                                   w3b, wt3b, w4b, wt4b, w2a, wtpq, w4a, wtrs,
                                   b2a, biasPQ, stats);

    // MLP1 (nodes)
    fused_mlp<true ><<<M_NODE / 64, 256, 0, stream>>>(inp, wt1a, b1a, wt1b, b1b, x1, stats + 0);
    bn_finalize<<<1, 256, 0, stream>>>(stats + 0, g1, be1, (float)M_NODE, sc + 0);

    // PQ = BN1(x1) @ [W2a_s | W2a_r] + [b2a|0]  (BN1 folded into staging)
    { dim3 g(M_NODE / 64, 2); node_gemm<<<g, 256, 0, stream>>>(x1, sc + 0, wtpq, biasPQ, PQ); }

    // MLP2 (edges, pipelined B-stationary, T2 tiles/block) -> h2, stats2
    m2_kernel<<<M_EDGE / (64 * T2), 256, 0, stream>>>(PQ, wt2b, b2b, h2, stats + 512);
    bn_finalize<<<1, 256, 0, stream>>>(stats + 512, g2, be2, (float)M_EDGE, sc + 512);

    // edge2node (BN2 folded) + MLP3 (nodes)
    edge2node<<<M_NODE, 256, 0, stream>>>(h2, sc + 512, incb);
    fused_mlp<false><<<M_NODE / 64, 256, 0, stream>>>(incb, wt3a, b3a, wt3b, b3b, x3, stats + 1024);
    bn_finalize<<<1, 256, 0, stream>>>(stats + 1024, g3, be3, (float)M_NODE, sc + 1024);

    // BN2-folded skip weight + RS bias (depend on sc2), one launch
    prep2<<<257, 256, 0, stream>>>(w4a, sc + 512, b4a, wtsk, biasRS);
    // RS = BN3(x3) @ [W4a_s | W4a_r] + biasRS  (BN3 folded into staging)
    { dim3 g(M_NODE / 64, 2); node_gemm<<<g, 256, 0, stream>>>(x3, sc + 1024, wtrs, biasRS, RS); }

    // MLP4 (edges, W4b-stationary L2) -> h4, stats4
    m4_kernel<<<M_EDGE / 64, 256, 0, stream>>>(h2, wtsk, RS, wt4b, b4b, h4, stats + 1536);
    bn_finalize<<<1, 256, 0, stream>>>(stats + 1536, g4, be4, (float)M_EDGE, sc + 1536);

    // final fc with BN4 folded, fp32 output
    fc_kernel<<<M_EDGE / 8, 256, 0, stream>>>(h4, sc + 1536, fcw, fcb, (float*)d_out);
}

// Round 18
// 372.520 us; speedup vs baseline: 1.0789x; 1.0789x over previous
//
#include <hip/hip_runtime.h>

typedef __bf16 bf16_t;
typedef __bf16 bf16x8 __attribute__((ext_vector_type(8)));
typedef float  f32x4  __attribute__((ext_vector_type(4)));

#define NB    64
#define EB    4032            // NB*(NB-1)
#define BATCH 32
#define H     256
#define M_EDGE (BATCH*EB)     // 129024
#define M_NODE (BATCH*NB)     // 2048
#define T2    4               // m2: M-tiles per block
#define BN_EPS 1e-5f

__device__ __forceinline__ void load_lds16(const void* g, void* l) {
    __builtin_amdgcn_global_load_lds(
        (const __attribute__((address_space(1))) unsigned int*)g,
        (__attribute__((address_space(3))) unsigned int*)l, 16, 0, 0);
}
// fast ELU: v_exp_f32 (+mul) instead of ~35-inst expm1f; bf16-rounding dwarfs the error
__device__ __forceinline__ float elu(float v) { return v > 0.f ? v : __expf(v) - 1.f; }

// ---------------------------------------------------------------------------
// Fused 2-layer node MLP: out = ELU(ELU(A@W1+b1)@W2+b2), 64 rows/block, K1=256.
// ---------------------------------------------------------------------------
template<bool AF32>
__global__ __launch_bounds__(256)
void fused_mlp(const void* __restrict__ A0v,
               const bf16_t* __restrict__ W1t, const float* __restrict__ b1,
               const bf16_t* __restrict__ W2t, const float* __restrict__ b2,
               bf16_t* __restrict__ out, float* __restrict__ stats)
{
    const int m0 = blockIdx.x * 64;
    const int tid = threadIdx.x, wave = tid >> 6, lane = tid & 63;
    const int l15 = lane & 15, quad = lane >> 4;
    const int row = tid >> 2;
    const int cx8 = (((tid & 3) ^ ((tid >> 3) & 3))) * 8;
    const int sl8 = (tid & 3) * 8;
    const int xq8 = (quad ^ ((l15 >> 1) & 3)) * 8;

    __shared__ bf16_t h1s[64 * 264];
    __shared__ bf16_t Bs[256 * 32];
    __shared__ float  sred[512];

    const bf16_t* A0 = (const bf16_t*)A0v;

    f32x4 acc1[4][4];
#pragma unroll
    for (int t = 0; t < 4; ++t)
#pragma unroll
        for (int u = 0; u < 4; ++u) acc1[t][u] = (f32x4){0.f, 0.f, 0.f, 0.f};

    for (int k0 = 0; k0 < 256; k0 += 32) {
        bf16_t* ldsA = h1s + wave * 512;
        if (AF32) {
            const float* af = (const float*)A0v + (size_t)(m0 + row) * 256 + k0 + cx8;
            float4 lo = *(const float4*)af;
            float4 hi = *(const float4*)(af + 4);
            bf16x8 v;
            v[0]=(bf16_t)lo.x; v[1]=(bf16_t)lo.y; v[2]=(bf16_t)lo.z; v[3]=(bf16_t)lo.w;
            v[4]=(bf16_t)hi.x; v[5]=(bf16_t)hi.y; v[6]=(bf16_t)hi.z; v[7]=(bf16_t)hi.w;
            *(bf16x8*)&h1s[row * 32 + sl8] = v;
        } else {
            load_lds16(A0 + (size_t)(m0 + row) * 256 + k0 + cx8, ldsA);
        }
#pragma unroll
        for (int p = 0; p < 4; ++p)
            load_lds16(W1t + (size_t)(p * 64 + row) * 256 + k0 + cx8,
                       Bs + (p * 256 + wave * 64) * 8);
        __syncthreads();
        bf16x8 afr[4], bfr[4];
#pragma unroll
        for (int t = 0; t < 4; ++t)
            afr[t] = *(const bf16x8*)&h1s[(t * 16 + l15) * 32 + xq8];
#pragma unroll
        for (int u = 0; u < 4; ++u)
            bfr[u] = *(const bf16x8*)&Bs[(wave * 64 + u * 16 + l15) * 32 + xq8];
#pragma unroll
        for (int t = 0; t < 4; ++t)
#pragma unroll
            for (int u = 0; u < 4; ++u)
                acc1[t][u] = __builtin_amdgcn_mfma_f32_16x16x32_bf16(afr[t], bfr[u], acc1[t][u], 0, 0, 0);
        __syncthreads();
    }

#pragma unroll
    for (int u = 0; u < 4; ++u) {
        int   col = wave * 64 + u * 16 + l15;
        float bv  = b1[col];
#pragma unroll
        for (int t = 0; t < 4; ++t)
#pragma unroll
            for (int r = 0; r < 4; ++r)
                h1s[(t * 16 + quad * 4 + r) * 264 + col] = (bf16_t)elu(acc1[t][u][r] + bv);
    }
    sred[tid] = 0.f; sred[256 + tid] = 0.f;
    __syncthreads();

    f32x4 acc2[4][4];
#pragma unroll
    for (int t = 0; t < 4; ++t)
#pragma unroll
        for (int u = 0; u < 4; ++u) acc2[t][u] = (f32x4){0.f, 0.f, 0.f, 0.f};

    for (int k0 = 0; k0 < 256; k0 += 32) {
#pragma unroll
        for (int p = 0; p < 4; ++p)
            load_lds16(W2t + (size_t)(p * 64 + row) * 256 + k0 + cx8,
                       Bs + (p * 256 + wave * 64) * 8);
        __syncthreads();
        bf16x8 afr[4], bfr[4];
#pragma unroll
        for (int t = 0; t < 4; ++t)
            afr[t] = *(const bf16x8*)&h1s[(t * 16 + l15) * 264 + k0 + quad * 8];
#pragma unroll
        for (int u = 0; u < 4; ++u)
            bfr[u] = *(const bf16x8*)&Bs[(wave * 64 + u * 16 + l15) * 32 + xq8];
#pragma unroll
        for (int t = 0; t < 4; ++t)
#pragma unroll
            for (int u = 0; u < 4; ++u)
                acc2[t][u] = __builtin_amdgcn_mfma_f32_16x16x32_bf16(afr[t], bfr[u], acc2[t][u], 0, 0, 0);
        __syncthreads();
    }

#pragma unroll
    for (int u = 0; u < 4; ++u) {
        int   col = wave * 64 + u * 16 + l15;
        float bv  = b2[col];
        float s = 0.f, q = 0.f;
#pragma unroll
        for (int t = 0; t < 4; ++t)
#pragma unroll
            for (int r = 0; r < 4; ++r) {
                float v = elu(acc2[t][u][r] + bv);
                h1s[(t * 16 + quad * 4 + r) * 264 + col] = (bf16_t)v;
                s += v; q += v * v;
            }
        s += __shfl_xor(s, 16); s += __shfl_xor(s, 32);
        q += __shfl_xor(q, 16); q += __shfl_xor(q, 32);
        if (quad == 0) { atomicAdd(&sred[col], s); atomicAdd(&sred[256 + col], q); }
    }
    __syncthreads();
#pragma unroll
    for (int p = 0; p < 8; ++p) {
        int idx = p * 256 + tid;
        int r = idx >> 5, ch = idx & 31;
        *(uint4*)&out[(size_t)(m0 + r) * H + ch * 8] = *(const uint4*)&h1s[r * 264 + ch * 8];
    }
    atomicAdd(&stats[tid],     sred[tid]);
    atomicAdd(&stats[H + tid], sred[256 + tid]);
}

// ---------------------------------------------------------------------------
// Node GEMM w/ BN fold on A (sc computed in-kernel from raw stats):
// out[M,512] = (A*scale+shift)[M,256] @ Wt^T + bias.
// ---------------------------------------------------------------------------
__global__ __launch_bounds__(256)
void node_gemm(const bf16_t* __restrict__ A, const float* __restrict__ statsIn,
               const float* __restrict__ g, const float* __restrict__ beta, float Mcnt,
               const bf16_t* __restrict__ Wt, const float* __restrict__ bias,
               float* __restrict__ out)
{
    const int m0 = blockIdx.x * 64;
    const int nb = blockIdx.y * 256;
    const int tid = threadIdx.x, wave = tid >> 6, lane = tid & 63;
    const int l15 = lane & 15, quad = lane >> 4;
    const int row = tid >> 2;
    const int cx8 = (((tid & 3) ^ ((tid >> 3) & 3))) * 8;
    const int sl8 = (tid & 3) * 8;
    const int xq8 = (quad ^ ((l15 >> 1) & 3)) * 8;
    __shared__ bf16_t As[64 * 32];
    __shared__ bf16_t Bs[256 * 32];
    __shared__ float  ss[512];   // scale | shift

    {   // BN finalize inline (replaces bn_finalize dispatch)
        float mean = statsIn[tid] / Mcnt;
        float var  = statsIn[256 + tid] / Mcnt - mean * mean;
        float scl  = g[tid] * rsqrtf(var + BN_EPS);
        ss[tid]       = scl;
        ss[256 + tid] = beta[tid] - mean * scl;
    }
    __syncthreads();

    f32x4 acc[4][4];
#pragma unroll
    for (int t = 0; t < 4; ++t)
#pragma unroll
        for (int u = 0; u < 4; ++u) acc[t][u] = (f32x4){0.f, 0.f, 0.f, 0.f};

    for (int k0 = 0; k0 < 256; k0 += 32) {
        {   // BN-folded A staging (VGPR path)
            int kc = k0 + cx8;
            bf16x8 v = *(const bf16x8*)(A + (size_t)(m0 + row) * 256 + kc);
            bf16x8 w;
#pragma unroll
            for (int j = 0; j < 8; ++j)
                w[j] = (bf16_t)((float)v[j] * ss[kc + j] + ss[256 + kc + j]);
            *(bf16x8*)&As[row * 32 + sl8] = w;
        }
#pragma unroll
        for (int p = 0; p < 4; ++p)
            load_lds16(Wt + (size_t)(nb + p * 64 + row) * 256 + k0 + cx8,
                       Bs + (p * 256 + wave * 64) * 8);
        __syncthreads();
        bf16x8 afr[4], bfr[4];
#pragma unroll
        for (int t = 0; t < 4; ++t)
            afr[t] = *(const bf16x8*)&As[(t * 16 + l15) * 32 + xq8];
#pragma unroll
        for (int u = 0; u < 4; ++u)
            bfr[u] = *(const bf16x8*)&Bs[(wave * 64 + u * 16 + l15) * 32 + xq8];
#pragma unroll
        for (int t = 0; t < 4; ++t)
#pragma unroll
            for (int u = 0; u < 4; ++u)
                acc[t][u] = __builtin_amdgcn_mfma_f32_16x16x32_bf16(afr[t], bfr[u], acc[t][u], 0, 0, 0);
        __syncthreads();
    }
#pragma unroll
    for (int u = 0; u < 4; ++u) {
        int col = nb + wave * 64 + u * 16 + l15;
        float bv = bias[col];
#pragma unroll
        for (int t = 0; t < 4; ++t)
#pragma unroll
            for (int r = 0; r < 4; ++r)
                out[(size_t)(m0 + t * 16 + quad * 4 + r) * 512 + col] = acc[t][u][r] + bv;
    }
}

// ---------------------------------------------------------------------------
// MLP2, PIPELINED B-STATIONARY (R13 winner): W2b frags in regs; T2 M-tiles
// per block; A tile t+1 computed into alt LDS buffer while MFMA consumes t.
// ---------------------------------------------------------------------------
__global__ __launch_bounds__(256, 2)
void m2_kernel(const float* __restrict__ PQ, const bf16_t* __restrict__ W2t,
               const float* __restrict__ b2, bf16_t* __restrict__ out,
               float* __restrict__ stats)
{
    const int tile0 = blockIdx.x * T2;   // 64-row tiles
    const int tid = threadIdx.x, wave = tid >> 6, lane = tid & 63;
    const int l15 = lane & 15, quad = lane >> 4;

    __shared__ bf16_t Abuf[2][64 * 264];
    __shared__ float  sred[512];

    bf16x8 Breg[32];
#pragma unroll
    for (int ks = 0; ks < 8; ++ks)
#pragma unroll
        for (int u = 0; u < 4; ++u) {
            int col = wave * 64 + u * 16 + l15;
            Breg[ks * 4 + u] = *(const bf16x8*)(W2t + (size_t)col * 256 + ks * 32 + quad * 8);
        }
    sred[tid] = 0.f; sred[256 + tid] = 0.f;

    auto computeA = [&](int t, int b) {
        int row = tid >> 2;
        int m = (tile0 + t) * 64 + row;
        int bb = m / EB, e = m - bb * EB;
        int sn = e / (NB - 1), rr = e - sn * (NB - 1);
        int rc = rr + (rr >= sn ? 1 : 0);
        const float* Prow = PQ + (size_t)(bb * NB + sn) * 512;
        const float* Qrow = PQ + (size_t)(bb * NB + rc) * 512 + 256;
        int c0 = (tid & 3) * 64;
#pragma unroll
        for (int j = 0; j < 8; ++j) {
            int c = c0 + j * 8;
            float4 p0 = *(const float4*)(Prow + c);
            float4 p1 = *(const float4*)(Prow + c + 4);
            float4 q0 = *(const float4*)(Qrow + c);
            float4 q1 = *(const float4*)(Qrow + c + 4);
            bf16x8 v;
            v[0]=(bf16_t)elu(p0.x+q0.x); v[1]=(bf16_t)elu(p0.y+q0.y);
            v[2]=(bf16_t)elu(p0.z+q0.z); v[3]=(bf16_t)elu(p0.w+q0.w);
            v[4]=(bf16_t)elu(p1.x+q1.x); v[5]=(bf16_t)elu(p1.y+q1.y);
            v[6]=(bf16_t)elu(p1.z+q1.z); v[7]=(bf16_t)elu(p1.w+q1.w);
            *(bf16x8*)&Abuf[b][row * 264 + c] = v;
        }
    };

    computeA(0, 0);
    __syncthreads();

    for (int t = 0; t < T2; ++t) {
        const int cur = t & 1, nxt = cur ^ 1;
        if (t + 1 < T2) computeA(t + 1, nxt);

        f32x4 acc[4][4];
#pragma unroll
        for (int a = 0; a < 4; ++a)
#pragma unroll
            for (int u = 0; u < 4; ++u) acc[a][u] = (f32x4){0.f, 0.f, 0.f, 0.f};
#pragma unroll
        for (int ks = 0; ks < 8; ++ks) {
            bf16x8 afr[4];
#pragma unroll
            for (int a = 0; a < 4; ++a)
                afr[a] = *(const bf16x8*)&Abuf[cur][(a * 16 + l15) * 264 + ks * 32 + quad * 8];
#pragma unroll
            for (int a = 0; a < 4; ++a)
#pragma unroll
                for (int u = 0; u < 4; ++u)
                    acc[a][u] = __builtin_amdgcn_mfma_f32_16x16x32_bf16(afr[a], Breg[ks * 4 + u], acc[a][u], 0, 0, 0);
        }
        __syncthreads();

#pragma unroll
        for (int u = 0; u < 4; ++u) {
            int   col = wave * 64 + u * 16 + l15;
            float bv  = b2[col];
            float s = 0.f, q = 0.f;
#pragma unroll
            for (int a = 0; a < 4; ++a)
#pragma unroll
                for (int r = 0; r < 4; ++r) {
                    float v = elu(acc[a][u][r] + bv);
                    Abuf[cur][(a * 16 + quad * 4 + r) * 264 + col] = (bf16_t)v;
                    s += v; q += v * v;
                }
            s += __shfl_xor(s, 16); s += __shfl_xor(s, 32);
            q += __shfl_xor(q, 16); q += __shfl_xor(q, 32);
            if (quad == 0) { atomicAdd(&sred[col], s); atomicAdd(&sred[256 + col], q); }
        }
        __syncthreads();

        size_t m0 = (size_t)(tile0 + t) * 64;
#pragma unroll
        for (int p = 0; p < 8; ++p) {
            int idx = p * 256 + tid;
            int r = idx >> 5, ch = idx & 31;
            *(uint4*)&out[(m0 + r) * H + ch * 8] = *(const uint4*)&Abuf[cur][r * 264 + ch * 8];
        }
        __syncthreads();
    }
    atomicAdd(&stats[tid],     sred[tid]);
    atomicAdd(&stats[H + tid], sred[256 + tid]);
}

// ---------------------------------------------------------------------------
// MLP4 fused (R10/R16 proven form): per-iter A+B staging; spill acc1,
// row-wise coalesced RS add + ELU; L2 GEMM with W4b -> h4 + BN stats.
// ---------------------------------------------------------------------------
__global__ __launch_bounds__(256)
void m4_kernel(const bf16_t* __restrict__ h2, const bf16_t* __restrict__ Wskt,
               const float* __restrict__ RS, const bf16_t* __restrict__ W2t,
               const float* __restrict__ b2, bf16_t* __restrict__ out,
               float* __restrict__ stats)
{
    const int m0 = blockIdx.x * 64;
    const int tid = threadIdx.x, wave = tid >> 6, lane = tid & 63;
    const int l15 = lane & 15, quad = lane >> 4;
    const int row = tid >> 2;
    const int cx8 = (((tid & 3) ^ ((tid >> 3) & 3))) * 8;
    const int xq8 = (quad ^ ((l15 >> 1) & 3)) * 8;

    __shared__ bf16_t h1s[64 * 264];
    __shared__ bf16_t Bs[256 * 32];
    __shared__ float  sred[512];
    __shared__ int    sndN[64], rcvN[64];

    if (tid < 64) {
        int m = m0 + tid, bb = m / EB, e = m - bb * EB;
        int sn = e / (NB - 1), rr = e - sn * (NB - 1);
        int rc = rr + (rr >= sn ? 1 : 0);
        sndN[tid] = bb * NB + sn;
        rcvN[tid] = bb * NB + rc;
    }

    f32x4 acc1[4][4];
#pragma unroll
    for (int t = 0; t < 4; ++t)
#pragma unroll
        for (int u = 0; u < 4; ++u) acc1[t][u] = (f32x4){0.f, 0.f, 0.f, 0.f};

    for (int k0 = 0; k0 < 256; k0 += 32) {
        load_lds16(h2 + (size_t)(m0 + row) * 256 + k0 + cx8, h1s + wave * 512);
#pragma unroll
        for (int p = 0; p < 4; ++p)
            load_lds16(Wskt + (size_t)(p * 64 + row) * 256 + k0 + cx8,
                       Bs + (p * 256 + wave * 64) * 8);
        __syncthreads();
        bf16x8 afr[4], bfr[4];
#pragma unroll
        for (int t = 0; t < 4; ++t)
            afr[t] = *(const bf16x8*)&h1s[(t * 16 + l15) * 32 + xq8];
#pragma unroll
        for (int u = 0; u < 4; ++u)
            bfr[u] = *(const bf16x8*)&Bs[(wave * 64 + u * 16 + l15) * 32 + xq8];
#pragma unroll
        for (int t = 0; t < 4; ++t)
#pragma unroll
            for (int u = 0; u < 4; ++u)
                acc1[t][u] = __builtin_amdgcn_mfma_f32_16x16x32_bf16(afr[t], bfr[u], acc1[t][u], 0, 0, 0);
        __syncthreads();
    }

    // spill acc1 (pre-activation) to LDS in row-major layout
#pragma unroll
    for (int u = 0; u < 4; ++u) {
        int col = wave * 64 + u * 16 + l15;
#pragma unroll
        for (int t = 0; t < 4; ++t)
#pragma unroll
            for (int r = 0; r < 4; ++r)
                h1s[(t * 16 + quad * 4 + r) * 264 + col] = (bf16_t)acc1[t][u][r];
    }
    sred[tid] = 0.f; sred[256 + tid] = 0.f;
    __syncthreads();

    // row-wise coalesced RS add + ELU (send row L1-cached: <=2 senders/block)
    {
        const float* Srow = RS + (size_t)sndN[row] * 512;
        const float* Rrow = RS + (size_t)rcvN[row] * 512 + 256;
        int c0 = (tid & 3) * 64;
#pragma unroll
        for (int j = 0; j < 8; ++j) {
            int c = c0 + j * 8;
            bf16x8 h = *(const bf16x8*)&h1s[row * 264 + c];
            float4 s0 = *(const float4*)(Srow + c);
            float4 s1 = *(const float4*)(Srow + c + 4);
            float4 r0 = *(const float4*)(Rrow + c);
            float4 r1 = *(const float4*)(Rrow + c + 4);
            bf16x8 v;
            v[0]=(bf16_t)elu((float)h[0]+s0.x+r0.x); v[1]=(bf16_t)elu((float)h[1]+s0.y+r0.y);
            v[2]=(bf16_t)elu((float)h[2]+s0.z+r0.z); v[3]=(bf16_t)elu((float)h[3]+s0.w+r0.w);
            v[4]=(bf16_t)elu((float)h[4]+s1.x+r1.x); v[5]=(bf16_t)elu((float)h[5]+s1.y+r1.y);
            v[6]=(bf16_t)elu((float)h[6]+s1.z+r1.z); v[7]=(bf16_t)elu((float)h[7]+s1.w+r1.w);
            *(bf16x8*)&h1s[row * 264 + c] = v;
        }
    }
    __syncthreads();

    f32x4 acc2[4][4];
#pragma unroll
    for (int t = 0; t < 4; ++t)
#pragma unroll
        for (int u = 0; u < 4; ++u) acc2[t][u] = (f32x4){0.f, 0.f, 0.f, 0.f};

    for (int k0 = 0; k0 < 256; k0 += 32) {
#pragma unroll
        for (int p = 0; p < 4; ++p)
            load_lds16(W2t + (size_t)(p * 64 + row) * 256 + k0 + cx8,
                       Bs + (p * 256 + wave * 64) * 8);
        __syncthreads();
        bf16x8 afr[4], bfr[4];
#pragma unroll
        for (int t = 0; t < 4; ++t)
            afr[t] = *(const bf16x8*)&h1s[(t * 16 + l15) * 264 + k0 + quad * 8];
#pragma unroll
        for (int u = 0; u < 4; ++u)
            bfr[u] = *(const bf16x8*)&Bs[(wave * 64 + u * 16 + l15) * 32 + xq8];
#pragma unroll
        for (int t = 0; t < 4; ++t)
#pragma unroll
            for (int u = 0; u < 4; ++u)
                acc2[t][u] = __builtin_amdgcn_mfma_f32_16x16x32_bf16(afr[t], bfr[u], acc2[t][u], 0, 0, 0);
        __syncthreads();
    }

#pragma unroll
    for (int u = 0; u < 4; ++u) {
        int   col = wave * 64 + u * 16 + l15;
        float bv  = b2[col];
        float s = 0.f, q = 0.f;
#pragma unroll
        for (int t = 0; t < 4; ++t)
#pragma unroll
            for (int r = 0; r < 4; ++r) {
                float v = elu(acc2[t][u][r] + bv);
                h1s[(t * 16 + quad * 4 + r) * 264 + col] = (bf16_t)v;
                s += v; q += v * v;
            }
        s += __shfl_xor(s, 16); s += __shfl_xor(s, 32);
        q += __shfl_xor(q, 16); q += __shfl_xor(q, 32);
        if (quad == 0) { atomicAdd(&sred[col], s); atomicAdd(&sred[256 + col], q); }
    }
    __syncthreads();
#pragma unroll
    for (int p = 0; p < 8; ++p) {
        int idx = p * 256 + tid;
        int r = idx >> 5, ch = idx & 31;
        *(uint4*)&out[(size_t)(m0 + r) * H + ch * 8] = *(const uint4*)&h1s[r * 264 + ch * 8];
    }
    atomicAdd(&stats[tid],     sred[tid]);
    atomicAdd(&stats[H + tid], sred[256 + tid]);
}

// ---------------------------------------------------------------------------
// prep: all static weight prep in ONE kernel (block-index dispatch).
// ---------------------------------------------------------------------------
__global__ void prep(const float* __restrict__ w1a, bf16_t* __restrict__ wt1a,
                     const float* __restrict__ w1b, bf16_t* __restrict__ wt1b,
                     const float* __restrict__ w2b, bf16_t* __restrict__ wt2b,
                     const float* __restrict__ w3a, bf16_t* __restrict__ wt3a,
                     const float* __restrict__ w3b, bf16_t* __restrict__ wt3b,
                     const float* __restrict__ w4b, bf16_t* __restrict__ wt4b,
                     const float* __restrict__ w2a, bf16_t* __restrict__ wtpq,
                     const float* __restrict__ w4a, bf16_t* __restrict__ wtrs,
                     const float* __restrict__ b2a, float* __restrict__ biasPQ,
                     float* __restrict__ stats)
{
    int blk = blockIdx.x, tid = threadIdx.x;
    if (blk < 1536) {
        int grp = blk >> 8, lb = blk & 255;
        const float* w; bf16_t* wt;
        switch (grp) {
            case 0: w = w1a; wt = wt1a; break;
            case 1: w = w1b; wt = wt1b; break;
            case 2: w = w2b; wt = wt2b; break;
            case 3: w = w3a; wt = wt3a; break;
            case 4: w = w3b; wt = wt3b; break;
            default: w = w4b; wt = wt4b; break;
        }
        int idx = lb * 256 + tid;
        int k = idx >> 8, n = idx & 255;
        wt[n * 256 + k] = (bf16_t)w[idx];
    } else if (blk < 2560) {
        int lb = blk - 1536;
        const float* w = (lb < 512) ? w2a : w4a;
        bf16_t* wt = (lb < 512) ? wtpq : wtrs;
        int c = lb & 511, k = tid;
        float v = (c < 256) ? w[k * 256 + c] : w[(256 + k) * 256 + (c - 256)];
        wt[c * 256 + k] = (bf16_t)v;
    } else if (blk == 2560) {
        biasPQ[tid] = b2a[tid];
        biasPQ[256 + tid] = 0.f;
    } else {
        for (int j = 0; j < 8; ++j) stats[j * 256 + tid] = 0.f;
    }
}

// prep2: blocks 0-255 build wsk; block 256 builds bias_rs. sc2 computed
// in-kernel from raw stats2 (bn_finalize folded in).
__global__ void prep2(const float* __restrict__ w4a, const float* __restrict__ stats2,
                      const float* __restrict__ g2, const float* __restrict__ be2,
                      const float* __restrict__ b4a, bf16_t* __restrict__ wt,
                      float* __restrict__ bias)
{
    __shared__ float sh2s[256];
    int blk = blockIdx.x, tid = threadIdx.x;
    float mean = stats2[tid] / (float)M_EDGE;
    float var  = stats2[256 + tid] / (float)M_EDGE - mean * mean;
    float scl  = g2[tid] * rsqrtf(var + BN_EPS);
    if (blk < 256) {
        wt[blk * 256 + tid] = (bf16_t)(w4a[(512 + tid) * 256 + blk] * scl);
    } else {
        sh2s[tid] = be2[tid] - mean * scl;
        __syncthreads();
        float acc = 0.f;
        for (int k = 0; k < 256; ++k)
            acc += sh2s[k] * w4a[(512 + k) * 256 + tid];
        bias[tid] = b4a[tid] + acc;
        bias[256 + tid] = 0.f;
    }
}

// edge2node w/ inline BN2 finalize
__global__ void edge2node(const bf16_t* __restrict__ x2, const float* __restrict__ stats2,
                          const float* __restrict__ g2, const float* __restrict__ be2,
                          bf16_t* __restrict__ inc)
{
    int bn = blockIdx.x, bb = bn >> 6, n = bn & 63;
    int g = threadIdx.x >> 5, t = threadIdx.x & 31;
    __shared__ float part[8][256];
    __shared__ float ss[512];
    {
        int c = threadIdx.x;
        float mean = stats2[c] / (float)M_EDGE;
        float var  = stats2[256 + c] / (float)M_EDGE - mean * mean;
        float scl  = g2[c] * rsqrtf(var + BN_EPS);
        ss[c]       = scl;
        ss[256 + c] = be2[c] - mean * scl;
    }
    const bf16_t* base = x2 + (size_t)bb * EB * H;
    float a[8] = {0.f,0.f,0.f,0.f,0.f,0.f,0.f,0.f};
    for (int i = g; i < NB; i += 8) {
        if (i == n) continue;
        int e = i * (NB - 1) + n - (n > i ? 1 : 0);
        bf16x8 v = *(const bf16x8*)&base[(size_t)e * H + t * 8];
#pragma unroll
        for (int j = 0; j < 8; ++j) a[j] += (float)v[j];
    }
#pragma unroll
    for (int j = 0; j < 8; ++j) part[g][t * 8 + j] = a[j];
    __syncthreads();
    int c = threadIdx.x;
    float s = 0.f;
#pragma unroll
    for (int g2i = 0; g2i < 8; ++g2i) s += part[g2i][c];
    inc[(size_t)bn * H + c] = (bf16_t)(s * (1.f / 64.f) * ss[c] + ss[256 + c] * (63.f / 64.f));
}

// fc w/ inline BN4 finalize
__global__ void fc_kernel(const bf16_t* __restrict__ x4, const float* __restrict__ stats4,
                          const float* __restrict__ g4, const float* __restrict__ be4,
                          const float* __restrict__ fcw, const float* __restrict__ fcb,
                          float* __restrict__ out)
{
    __shared__ float ss[512];
    {
        int c = threadIdx.x;
        float mean = stats4[c] / (float)M_EDGE;
        float var  = stats4[256 + c] / (float)M_EDGE - mean * mean;
        float scl  = g4[c] * rsqrtf(var + BN_EPS);
        ss[c]       = scl;
        ss[256 + c] = be4[c] - mean * scl;
    }
    __syncthreads();
    int row  = blockIdx.x * 8 + (threadIdx.x >> 5);
    int t    = threadIdx.x & 31;
    bf16x8 v8 = *(const bf16x8*)(x4 + (size_t)row * H + t * 8);
    float s0 = 0.f, s1 = 0.f;
#pragma unroll
    for (int j = 0; j < 8; ++j) {
        int c = t * 8 + j;
        float v = (float)v8[j] * ss[c] + ss[256 + c];
        s0 += v * fcw[c * 2];
        s1 += v * fcw[c * 2 + 1];
    }
#pragma unroll
    for (int off = 16; off; off >>= 1) {
        s0 += __shfl_down(s0, off, 32);
        s1 += __shfl_down(s1, off, 32);
    }
    if (t == 0) {
        out[(size_t)row * 2]     = s0 + fcb[0];
        out[(size_t)row * 2 + 1] = s1 + fcb[1];
    }
}

// ---------------------------------------------------------------------------
extern "C" void kernel_launch(void* const* d_in, const int* in_sizes, int n_in,
                              void* d_out, int out_size, void* d_ws, size_t ws_size,
                              hipStream_t stream)
{
    (void)in_sizes; (void)n_in; (void)out_size; (void)ws_size;
    const float* inp = (const float*)d_in[0];
    const float* w1a = (const float*)d_in[3];  const float* b1a = (const float*)d_in[4];
    const float* w1b = (const float*)d_in[5];  const float* b1b = (const float*)d_in[6];
    const float* g1  = (const float*)d_in[7];  const float* be1 = (const float*)d_in[8];
    const float* w2a = (const float*)d_in[9];  const float* b2a = (const float*)d_in[10];
    const float* w2b = (const float*)d_in[11]; const float* b2b = (const float*)d_in[12];
    const float* g2  = (const float*)d_in[13]; const float* be2 = (const float*)d_in[14];
    const float* w3a = (const float*)d_in[15]; const float* b3a = (const float*)d_in[16];
    const float* w3b = (const float*)d_in[17]; const float* b3b = (const float*)d_in[18];
    const float* g3  = (const float*)d_in[19]; const float* be3 = (const float*)d_in[20];
    const float* w4a = (const float*)d_in[21]; const float* b4a = (const float*)d_in[22];
    const float* w4b = (const float*)d_in[23]; const float* b4b = (const float*)d_in[24];
    const float* g4  = (const float*)d_in[25]; const float* be4 = (const float*)d_in[26];
    const float* fcw = (const float*)d_in[27]; const float* fcb = (const float*)d_in[28];

    char* p = (char*)d_ws;
    auto alloc = [&](size_t nbytes) { char* r = p; p += (nbytes + 255) & ~(size_t)255; return r; };

    bf16_t* wt1a = (bf16_t*)alloc(256 * 256 * 2);
    bf16_t* wt1b = (bf16_t*)alloc(256 * 256 * 2);
    bf16_t* wt2b = (bf16_t*)alloc(256 * 256 * 2);
    bf16_t* wt3a = (bf16_t*)alloc(256 * 256 * 2);
    bf16_t* wt3b = (bf16_t*)alloc(256 * 256 * 2);
    bf16_t* wt4b = (bf16_t*)alloc(256 * 256 * 2);
    bf16_t* wtpq = (bf16_t*)alloc(512 * 256 * 2);
    bf16_t* wtrs = (bf16_t*)alloc(512 * 256 * 2);
    bf16_t* wtsk = (bf16_t*)alloc(256 * 256 * 2);
    float*  biasPQ = (float*)alloc(512 * sizeof(float));
    float*  biasRS = (float*)alloc(512 * sizeof(float));
    float*  stats  = (float*)alloc(4 * 512 * sizeof(float));
    bf16_t* x1   = (bf16_t*)alloc((size_t)M_NODE * H * 2);
    bf16_t* incb = (bf16_t*)alloc((size_t)M_NODE * H * 2);
    bf16_t* x3   = (bf16_t*)alloc((size_t)M_NODE * H * 2);
    float*  PQ   = (float*)alloc((size_t)M_NODE * 512 * sizeof(float));
    float*  RS   = (float*)alloc((size_t)M_NODE * 512 * sizeof(float));
    bf16_t* h2   = (bf16_t*)alloc((size_t)M_EDGE * H * 2);
    bf16_t* h4   = (bf16_t*)alloc((size_t)M_EDGE * H * 2);

    // all static prep in one launch
    prep<<<2562, 256, 0, stream>>>(w1a, wt1a, w1b, wt1b, w2b, wt2b, w3a, wt3a,
                                   w3b, wt3b, w4b, wt4b, w2a, wtpq, w4a, wtrs,
                                   b2a, biasPQ, stats);

    // MLP1 (nodes) -> x1, stats1
    fused_mlp<true ><<<M_NODE / 64, 256, 0, stream>>>(inp, wt1a, b1a, wt1b, b1b, x1, stats + 0);

    // PQ = BN1(x1) @ [W2a_s | W2a_r] + [b2a|0]  (BN1 finalize+fold inline)
    { dim3 g(M_NODE / 64, 2);
      node_gemm<<<g, 256, 0, stream>>>(x1, stats + 0, g1, be1, (float)M_NODE, wtpq, biasPQ, PQ); }

    // MLP2 (edges, pipelined B-stationary, T2 tiles/block) -> h2, stats2
    m2_kernel<<<M_EDGE / (64 * T2), 256, 0, stream>>>(PQ, wt2b, b2b, h2, stats + 512);

    // edge2node (BN2 finalize+fold inline) + MLP3 (nodes)
    edge2node<<<M_NODE, 256, 0, stream>>>(h2, stats + 512, g2, be2, incb);
    fused_mlp<false><<<M_NODE / 64, 256, 0, stream>>>(incb, wt3a, b3a, wt3b, b3b, x3, stats + 1024);

    // BN2-folded skip weight + RS bias (sc2 computed inline)
    prep2<<<257, 256, 0, stream>>>(w4a, stats + 512, g2, be2, b4a, wtsk, biasRS);
    // RS = BN3(x3) @ [W4a_s | W4a_r] + biasRS  (BN3 finalize+fold inline)
    { dim3 g(M_NODE / 64, 2);
      node_gemm<<<g, 256, 0, stream>>>(x3, stats + 1024, g3, be3, (float)M_NODE, wtrs, biasRS, RS); }

    // MLP4 (edges, R10 form) -> h4, stats4
    m4_kernel<<<M_EDGE / 64, 256, 0, stream>>>(h2, wtsk, RS, wt4b, b4b, h4, stats + 1536);

    // final fc with BN4 finalize+fold inline, fp32 output
    fc_kernel<<<M_EDGE / 8, 256, 0, stream>>>(h4, stats + 1536, g4, be4, fcw, fcb, (float*)d_out);
}